// Round 21
// baseline (16.782 us; speedup 1.0000x reference)
//
#include <hip/hip_runtime.h>

// Sequential implicit-midpoint solve: y_k = y_{k-1} + DT*f_k - DT*tanh(W s_k),
// s_k = (y_k + y_{k-1})/2, one wave per batch element.
//
// R21 = R20 (15.88us, absmax 0.04345703) with the u-redistribution LDS trip
// replaced by ds_bpermute (register cross-lane, no write->read RAW wall):
//   D-layout (R15-verified): lane q<16 holds c_t[j] = u_{chain j}[16t+q];
//   lane 16+q holds preview u in c_t[0]. Target: lane L (comp L) needs
//   c_{L>>4}[j] from lane L&15 and preview from lane 16+(L&15).
//   => per j: 4 bpermute (one per tile reg) + 3 cndmask select by t=L>>4.
//   20 bpermute + 15 select replace 8 divergent DS writes + fence + 2 reads
//   + ~700cyc RAW latency (solo-wave LDS round-trips measured expensive
//   across R5/R10/R15). Also: parity pack selects removed (only even lanes'
//   p0/p1/p4 and odd lanes' p2/p3 are consumed -> pack unconditionally).
// Values moved are bit-identical -> absmax must stay 0.04345703.
//
// Structure: 5-chain round (4 steps + preview, R13 numerics), D[16x64] =
// S^T(A) @ W^T(B) via 16x mfma_f32_16x16x16f16; saddr addressing (R20).
// W pre-scaled by 2*log2(e): tanh(Ws) = 1 - 2/(exp2(u)+1).

#define SDIM 64
#define DT_C 0.05f
#define WSCALE 2.8853900817779268f  // 2*log2(e)
#define SPITCH 36                   // dword pitch per chain region (bank stagger)
#define FENCE_MASK 0x7F             // DS may not cross; all else may

typedef _Float16 v4h __attribute__((ext_vector_type(4)));
typedef float    v4f __attribute__((ext_vector_type(4)));
typedef __fp16   g2  __attribute__((ext_vector_type(2)));

#if defined(__HIP_DEVICE_COMPILE__)
#define MFMA16(A, B, C) __builtin_amdgcn_mfma_f32_16x16x16f16((A), (B), (C), 0, 0, 0)
#else
#define MFMA16(A, B, C) (C)  // host pass parses only
#endif

union H2U  { int i; g2 g; };
union V4HU { int2 i2; v4h h; g2 g[2]; };

__device__ __forceinline__ float recip_fast(float x) {
    float r; asm("v_rcp_f32 %0, %1" : "=v"(r) : "v"(x)); return r;
}
__device__ __forceinline__ float exp2_fast(float x) {
    float r; asm("v_exp_f32 %0, %1" : "=v"(r) : "v"(x)); return r;
}
__device__ __forceinline__ int pack_h2i(float a, float b) {
    H2U u; u.g = __builtin_amdgcn_cvt_pkrtz(a, b); return u.i;
}
__device__ __forceinline__ v4h pack_h4(float a, float b, float c, float d) {
    V4HU u;
    u.g[0] = __builtin_amdgcn_cvt_pkrtz(a, b);
    u.g[1] = __builtin_amdgcn_cvt_pkrtz(c, d);
    return u.h;
}
__device__ __forceinline__ v4h i2_as_h4(int2 v) { V4HU u; u.i2 = v; return u.h; }
__device__ __forceinline__ int dpp_nb(float s) {
    // quad_perm [1,0,3,2]: lane l <-> l^1
    return __builtin_amdgcn_update_dpp(0, __float_as_int(s), 0xB1, 0xF, 0xF, true);
}
__device__ __forceinline__ int imin(int a, int b) { return a < b ? a : b; }

// 5-chain matvec round: u_c = (W s_c)_lane, c=0..4.
// s-distribution via LDS (one trip); u-redistribution via ds_bpermute.
__device__ __forceinline__ void matvec5_mfma(int* lds_s,
                                             const v4h* __restrict__ wb,
                                             int l,
                                             float s0, float s1, float s2,
                                             float s3, float s4,
                                             float& u0, float& u1, float& u2,
                                             float& u3, float& u4)
{
    const bool odd = (l & 1);
    const int m = l >> 1;

    // pack pairs in parity-correct order (no selects: even lanes' p0/p1/p4
    // and odd lanes' p2/p3 are the only values consumed)
    const float n0 = __int_as_float(dpp_nb(s0));
    const float n1 = __int_as_float(dpp_nb(s1));
    const float n2 = __int_as_float(dpp_nb(s2));
    const float n3 = __int_as_float(dpp_nb(s3));
    const float n4 = __int_as_float(dpp_nb(s4));
    const int p0 = pack_h2i(s0, n0);  // even lane 2m: (s[2m], s[2m+1])
    const int p1 = pack_h2i(s1, n1);
    const int p4 = pack_h2i(s4, n4);
    const int p2 = pack_h2i(n2, s2);  // odd lane 2m+1: (s[2m], s[2m+1])
    const int p3 = pack_h2i(n3, s3);

    // chain-major layout: dword c*SPITCH + m
    if (!odd) {
        lds_s[0 * SPITCH + m] = p0;
        lds_s[1 * SPITCH + m] = p1;
        lds_s[4 * SPITCH + m] = p4;
    } else {
        lds_s[2 * SPITCH + m] = p2;
        lds_s[3 * SPITCH + m] = p3;
    }

    // ---- DS-only fence: s-writes precede A-frag reads (R9 lesson) ----
    asm volatile("" ::: "memory");
    __builtin_amdgcn_sched_barrier(FENCE_MASK);

    const int2* s2p = reinterpret_cast<const int2*>(lds_s);
    const int abase = 18 * (l & 15) + (l >> 4);
    const v4h a0 = i2_as_h4(s2p[abase + 0]);
    const v4h a1 = i2_as_h4(s2p[abase + 4]);
    const v4h a2 = i2_as_h4(s2p[abase + 8]);
    const v4h a3 = i2_as_h4(s2p[abase + 12]);

    v4f c0 = {0.f, 0.f, 0.f, 0.f};
    v4f c1 = c0, c2 = c0, c3 = c0;
    c0 = MFMA16(a0, wb[0],  c0);  c1 = MFMA16(a0, wb[4],  c1);
    c2 = MFMA16(a0, wb[8],  c2);  c3 = MFMA16(a0, wb[12], c3);
    c0 = MFMA16(a1, wb[1],  c0);  c1 = MFMA16(a1, wb[5],  c1);
    c2 = MFMA16(a1, wb[9],  c2);  c3 = MFMA16(a1, wb[13], c3);
    c0 = MFMA16(a2, wb[2],  c0);  c1 = MFMA16(a2, wb[6],  c1);
    c2 = MFMA16(a2, wb[10], c2);  c3 = MFMA16(a2, wb[14], c3);
    c0 = MFMA16(a3, wb[3],  c0);  c1 = MFMA16(a3, wb[7],  c1);
    c2 = MFMA16(a3, wb[11], c2);  c3 = MFMA16(a3, wb[15], c3);

    // u-redistribution via bpermute: lane L pulls c_{L>>4}[j] from lane L&15
    // (chains 0..3) and c_{L>>4}[0] from lane 16+(L&15) (preview).
    const int t = l >> 4;
    const int addr_q = (l & 15) << 2;
    const int addr_p = ((l & 15) + 16) << 2;

#define GATHER_U(jj, addr, dst)                                                       \
    {                                                                                 \
        const int b0_ = __builtin_amdgcn_ds_bpermute((addr), __float_as_int(c0[jj])); \
        const int b1_ = __builtin_amdgcn_ds_bpermute((addr), __float_as_int(c1[jj])); \
        const int b2_ = __builtin_amdgcn_ds_bpermute((addr), __float_as_int(c2[jj])); \
        const int b3_ = __builtin_amdgcn_ds_bpermute((addr), __float_as_int(c3[jj])); \
        const int s01_ = (t & 1) ? b1_ : b0_;                                         \
        const int s23_ = (t & 1) ? b3_ : b2_;                                         \
        dst = __int_as_float((t & 2) ? s23_ : s01_);                                  \
    }

    GATHER_U(0, addr_q, u0)
    GATHER_U(1, addr_q, u1)
    GATHER_U(2, addr_q, u2)
    GATHER_U(3, addr_q, u3)
    GATHER_U(0, addr_p, u4)
#undef GATHER_U
}

__global__ __launch_bounds__(64) void rnes_seq_kernel(
    const float* __restrict__ y0,
    const float* __restrict__ forces,
    const float* __restrict__ W,
    float* __restrict__ out,
    int n, int B)
{
    const int b = blockIdx.x;
    const int l = threadIdx.x;  // lane = state component

    // B-operand frags: wb[t*4+h] = W[16t+(l&15)][16h+4*(l>>4)+kk], scaled
    v4h wb[16];
    {
        const int co = l & 15, g = l >> 4;
        #pragma unroll
        for (int t = 0; t < 4; ++t) {
            #pragma unroll
            for (int h = 0; h < 4; ++h) {
                const float4 v = *reinterpret_cast<const float4*>(
                    W + (16 * t + co) * 64 + 16 * h + 4 * g);
                wb[t * 4 + h] = pack_h4(WSCALE * v.x, WSCALE * v.y,
                                        WSCALE * v.z, WSCALE * v.w);
            }
        }
    }

    __shared__ __align__(16) int lds_s[576];
    #pragma unroll
    for (int i = 0; i < 9; ++i) lds_s[i * 64 + l] = 0;

    const int BS = B * SDIM;  // row stride (uniform)

    const float* frow = forces + b * SDIM;
    float*       orow = out    + b * SDIM;

    float yprev = (y0 + b * SDIM)[l];
    orow[l] = yprev;  // out[0] = y0 pass-through

    // Seed tanh carry at s ~= y0
    float u0, u1, u2, u3, u4, tcar;
    matvec5_mfma(lds_s, wb, l, yprev, yprev, yprev, yprev, yprev,
                 u0, u1, u2, u3, u4);
    tcar = fmaf(-2.0f, recip_fast(exp2_fast(u0) + 1.0f), 1.0f);

    // force ring fR0..fR4 = f_k..f_{k+4}; scalar row clamps (dead-slot garbage)
    float fR0 = (frow + (size_t)imin(1, n - 1) * BS)[l];
    float fR1 = (frow + (size_t)imin(2, n - 1) * BS)[l];
    float fR2 = (frow + (size_t)imin(3, n - 1) * BS)[l];
    float fR3 = (frow + (size_t)imin(4, n - 1) * BS)[l];
    float fR4 = (frow + (size_t)imin(5, n - 1) * BS)[l];

    float* op = orow + BS;

    int k = 1;
    #pragma unroll 1
    for (; k + 3 < n; k += 4) {
        const float pf0 = (frow + (size_t)imin(k + 5, n - 1) * BS)[l];
        const float pf1 = (frow + (size_t)imin(k + 6, n - 1) * BS)[l];
        const float pf2 = (frow + (size_t)imin(k + 7, n - 1) * BS)[l];
        const float pf3 = (frow + (size_t)imin(k + 8, n - 1) * BS)[l];

        // speculative midpoints with carried tanh (R13 numerics, verbatim)
        const float d0 = fR0 - tcar;
        const float s0 = fmaf(0.5f * DT_C, d0, yprev);
        const float yp0 = fmaf(DT_C, d0, yprev);
        const float d1 = fR1 - tcar;
        const float s1 = fmaf(0.5f * DT_C, d1, yp0);
        const float yp1 = fmaf(DT_C, d1, yp0);
        const float d2 = fR2 - tcar;
        const float s2 = fmaf(0.5f * DT_C, d2, yp1);
        const float yp2 = fmaf(DT_C, d2, yp1);
        const float d3 = fR3 - tcar;
        const float s3 = fmaf(0.5f * DT_C, d3, yp2);
        const float yp3 = fmaf(DT_C, d3, yp2);
        const float d4 = fR4 - tcar;
        const float s4 = fmaf(0.5f * DT_C, d4, yp3);  // PREVIEW midpoint k+4

        matvec5_mfma(lds_s, wb, l, s0, s1, s2, s3, s4, u0, u1, u2, u3, u4);

        const float r0 = recip_fast(exp2_fast(u0) + 1.0f);
        const float r1 = recip_fast(exp2_fast(u1) + 1.0f);
        const float r2 = recip_fast(exp2_fast(u2) + 1.0f);
        const float r3 = recip_fast(exp2_fast(u3) + 1.0f);
        const float r4 = recip_fast(exp2_fast(u4) + 1.0f);

        // exact-recurrence corrections with fresh tanh
        const float y1c = fmaf(2.0f * DT_C, r0, fmaf(DT_C, fR0, yprev) - DT_C);
        const float y2c = fmaf(2.0f * DT_C, r1, fmaf(DT_C, fR1, y1c) - DT_C);
        const float y3c = fmaf(2.0f * DT_C, r2, fmaf(DT_C, fR2, y2c) - DT_C);
        const float y4c = fmaf(2.0f * DT_C, r3, fmaf(DT_C, fR3, y3c) - DT_C);

        op[l] = y1c;
        (op + BS)[l] = y2c;
        (op + 2 * BS)[l] = y3c;
        (op + 3 * BS)[l] = y4c;
        op += 4 * BS;

        yprev = y4c;
        tcar = fmaf(-2.0f, r4, 1.0f);  // preview tanh -> next round's carry
        fR0 = fR4; fR1 = pf0; fR2 = pf1; fR3 = pf2; fR4 = pf3;
    }

    // generic 1-step tail (not hit for n=65)
    #pragma unroll 1
    for (; k < n; ++k) {
        const float s = fmaf(0.5f * DT_C, fR0 - tcar, yprev);
        matvec5_mfma(lds_s, wb, l, s, s, s, s, s, u0, u1, u2, u3, u4);
        const float r = recip_fast(exp2_fast(u0) + 1.0f);
        const float y = fmaf(2.0f * DT_C, r, fmaf(DT_C, fR0, yprev) - DT_C);
        op[l] = y;
        op += BS;
        yprev = y;
        tcar = fmaf(-2.0f, r, 1.0f);
        fR0 = fR1; fR1 = fR2; fR2 = fR3; fR3 = fR4;
    }
}

extern "C" void kernel_launch(void* const* d_in, const int* in_sizes, int n_in,
                              void* d_out, int out_size, void* d_ws, size_t ws_size,
                              hipStream_t stream) {
    const float* y0     = (const float*)d_in[0];   // (B, S)
    const float* forces = (const float*)d_in[1];   // (n, B, S)
    const float* W      = (const float*)d_in[2];   // (S, S)
    float* out = (float*)d_out;                    // (n, B, S)

    const int BS = in_sizes[0];       // B * S
    const int B  = BS / SDIM;         // 128
    const int n  = in_sizes[1] / BS;  // 65

    rnes_seq_kernel<<<B, SDIM, 0, stream>>>(y0, forces, W, out, n, B);
}

// Round 22
// 15.535 us; speedup vs baseline: 1.0803x; 1.0803x over previous
//
#include <hip/hip_runtime.h>

// Sequential implicit-midpoint solve: y_k = y_{k-1} + DT*f_k - DT*tanh(W s_k),
// s_k = (y_k + y_{k-1})/2, one wave per batch element.
//
// R22: PIPELINED 2-ITERATION SCHEME, 16 chains per MFMA round, 8-step blocks.
//   Round r chains: 0..7  = iter-2 midpoints of block r-1 (from its y^1),
//                   8..15 = iter-1 midpoints of block r   (tcar predictor).
//   Round r output: r2 -> FINALIZE block r-1 (exact recurrence, stores);
//                   r1 -> y^1(block r) -> iter-2 midpoints m2'(block r),
//                         tcar = t1(block r, step 8),
//                         predictor midpoints m1'(block r+1).
//   64 steps = 8 blocks -> seed + 9 rounds = 10 MFMA rounds (vs 17 in R20).
//   Every step's tanh is evaluated twice (stale-predicted, then refined from
//   y^1); final y uses the refined value => error ~ NFP=2 quality.
//
// Verified machinery kept verbatim: wb B-frags, A-frag addressing (18c+g),
// MFMA_BLOCK roles, D-layout, fence pattern (mem clobber + sched_barrier 0x7F),
// saddr addressing with scalar row clamps (R20).
// New: 16-chain s-write, branchless: lane l writes chains {2i+(l&1)} at
//   lds_s[36*(2i+(l&1)) + (l>>1)] (parity-matched pack, 2/bank = free);
// u-redistribution buffer float4 lds_u4[t'][comp]: writes/reads are
//   contiguous 1KB per instruction (balanced, conflict-free).
// W pre-scaled by 2*log2(e): tanh(Ws) = 1 - 2/(exp2(u)+1).

#define SDIM 64
#define DT_C 0.05f
#define WSCALE 2.8853900817779268f  // 2*log2(e)
#define FENCE_MASK 0x7F             // DS may not cross; all else may

typedef _Float16 v4h __attribute__((ext_vector_type(4)));
typedef float    v4f __attribute__((ext_vector_type(4)));
typedef __fp16   g2  __attribute__((ext_vector_type(2)));

#if defined(__HIP_DEVICE_COMPILE__)
#define MFMA16(A, B, C) __builtin_amdgcn_mfma_f32_16x16x16f16((A), (B), (C), 0, 0, 0)
#else
#define MFMA16(A, B, C) (C)  // host pass parses only
#endif

union H2U  { int i; g2 g; };
union V4HU { int2 i2; v4h h; g2 g[2]; };

__device__ __forceinline__ float recip_fast(float x) {
    float r; asm("v_rcp_f32 %0, %1" : "=v"(r) : "v"(x)); return r;
}
__device__ __forceinline__ float exp2_fast(float x) {
    float r; asm("v_exp_f32 %0, %1" : "=v"(r) : "v"(x)); return r;
}
__device__ __forceinline__ int pack_h2i(float a, float b) {
    H2U u; u.g = __builtin_amdgcn_cvt_pkrtz(a, b); return u.i;
}
__device__ __forceinline__ v4h pack_h4(float a, float b, float c, float d) {
    V4HU u;
    u.g[0] = __builtin_amdgcn_cvt_pkrtz(a, b);
    u.g[1] = __builtin_amdgcn_cvt_pkrtz(c, d);
    return u.h;
}
__device__ __forceinline__ v4h i2_as_h4(int2 v) { V4HU u; u.i2 = v; return u.h; }
__device__ __forceinline__ int dpp_nb(float s) {
    // quad_perm [1,0,3,2]: lane l <-> l^1
    return __builtin_amdgcn_update_dpp(0, __float_as_int(s), 0xB1, 0xF, 0xF, true);
}
__device__ __forceinline__ int imin(int a, int b) { return a < b ? a : b; }

#define MFMA_BLOCK(ac0, ac1, ac2, ac3, A0, A1, A2, A3, wb)                  \
    ac0 = MFMA16(A0, wb[0],  ac0);  ac1 = MFMA16(A0, wb[4],  ac1);          \
    ac2 = MFMA16(A0, wb[8],  ac2);  ac3 = MFMA16(A0, wb[12], ac3);          \
    ac0 = MFMA16(A1, wb[1],  ac0);  ac1 = MFMA16(A1, wb[5],  ac1);          \
    ac2 = MFMA16(A1, wb[9],  ac2);  ac3 = MFMA16(A1, wb[13], ac3);          \
    ac0 = MFMA16(A2, wb[2],  ac0);  ac1 = MFMA16(A2, wb[6],  ac1);          \
    ac2 = MFMA16(A2, wb[10], ac2);  ac3 = MFMA16(A2, wb[14], ac3);          \
    ac0 = MFMA16(A3, wb[3],  ac0);  ac1 = MFMA16(A3, wb[7],  ac1);          \
    ac2 = MFMA16(A3, wb[11], ac2);  ac3 = MFMA16(A3, wb[15], ac3)

__global__ __launch_bounds__(64) void rnes_pipe_kernel(
    const float* __restrict__ y0,
    const float* __restrict__ forces,
    const float* __restrict__ W,
    float* __restrict__ out,
    int n, int B)
{
    const int b = blockIdx.x;
    const int l = threadIdx.x;
    const bool odd = (l & 1);

    // B-operand frags (R15-verified): wb[t*4+h] = W[16t+(l&15)][16h+4*(l>>4)+kk]
    v4h wb[16];
    {
        const int co = l & 15, g = l >> 4;
        #pragma unroll
        for (int t = 0; t < 4; ++t) {
            #pragma unroll
            for (int h = 0; h < 4; ++h) {
                const float4 v = *reinterpret_cast<const float4*>(
                    W + (16 * t + co) * 64 + 16 * h + 4 * g);
                wb[t * 4 + h] = pack_h4(WSCALE * v.x, WSCALE * v.y,
                                        WSCALE * v.z, WSCALE * v.w);
            }
        }
    }

    __shared__ __align__(16) int    lds_s[576];    // 16 chains x 36 ints
    __shared__ __align__(16) float4 lds_u4[1024];  // [t'][comp] 16KB

    const int BS = B * SDIM;
    const float* frow = forces + b * SDIM;
    float*       orow = out    + b * SDIM;

    const float y0v = (y0 + b * SDIM)[l];
    orow[l] = y0v;
    float yfin = y0v;

    const int base_s = 36 * (l & 1) + (l >> 1);
    const int abase  = 18 * (l & 15) + (l >> 4);   // int2 units
    const int uw     = (l >> 4) * 256 + (l & 15);  // float4 units

    // ---- SEED round: all 16 chains = y0; tcar = tanh(W y0) ----
    float tcar;
    {
        const float nb = __int_as_float(dpp_nb(y0v));
        const int sel = odd ? pack_h2i(nb, y0v) : pack_h2i(y0v, nb);
        #pragma unroll
        for (int i = 0; i < 8; ++i) lds_s[base_s + 72 * i] = sel;
        asm volatile("" ::: "memory");
        __builtin_amdgcn_sched_barrier(FENCE_MASK);

        const int2* s2p = reinterpret_cast<const int2*>(lds_s);
        const v4h a0 = i2_as_h4(s2p[abase + 0]);
        const v4h a1 = i2_as_h4(s2p[abase + 4]);
        const v4h a2 = i2_as_h4(s2p[abase + 8]);
        const v4h a3 = i2_as_h4(s2p[abase + 12]);
        v4f c0 = {0.f, 0.f, 0.f, 0.f}, c1 = c0, c2 = c0, c3 = c0;
        MFMA_BLOCK(c0, c1, c2, c3, a0, a1, a2, a3, wb);

        lds_u4[uw + 0]  = make_float4(c0[0], c0[1], c0[2], c0[3]);
        lds_u4[uw + 16] = make_float4(c1[0], c1[1], c1[2], c1[3]);
        lds_u4[uw + 32] = make_float4(c2[0], c2[1], c2[2], c2[3]);
        lds_u4[uw + 48] = make_float4(c3[0], c3[1], c3[2], c3[3]);
        asm volatile("" ::: "memory");
        __builtin_amdgcn_sched_barrier(FENCE_MASK);

        const float4 q0 = lds_u4[l];  // chains 0..3 at comp l; chain0 = .x
        tcar = fmaf(-2.f, recip_fast(exp2_fast(q0.x) + 1.f), 1.f);
    }

    // force blocks: fa = block r-1, fb = block r, fc = block r+1
    float fa[8], fb[8], fc[8];
    #pragma unroll
    for (int j = 0; j < 8; ++j) {
        fb[j] = (frow + (size_t)imin(1 + j, n - 1) * BS)[l];
        fc[j] = (frow + (size_t)imin(9 + j, n - 1) * BS)[l];
        fa[j] = fb[j];  // dummy for r=1 (finalize skipped)
    }

    // m1 = iter-1 midpoints of block 1 (tcar predictor); m2 dummy for r=1
    float m1[8], m2[8];
    {
        float yh = y0v;
        #pragma unroll
        for (int j = 0; j < 8; ++j) {
            const float d = fb[j] - tcar;
            m1[j] = fmaf(0.5f * DT_C, d, yh);
            yh = fmaf(DT_C, d, yh);
            m2[j] = m1[j];
        }
    }

    float* op = orow + BS;                 // row 1
    const int R = ((n - 1) + 7) / 8 + 1;   // n=65 -> 9

    #pragma unroll 1
    for (int r = 1; r <= R; ++r) {
        // prefetch block r+2 forces (rows 8r+9 .. 8r+16, clamped)
        float fd[8];
        #pragma unroll
        for (int j = 0; j < 8; ++j)
            fd[j] = (frow + (size_t)imin(8 * r + 9 + j, n - 1) * BS)[l];

        // pack & write 16 chains: c = 0..7 -> m2[c]; c = 8..15 -> m1[c-8].
        // lane parity writes parity-matched chains: branchless select.
        #pragma unroll
        for (int i = 0; i < 8; ++i) {
            const float vE = (i < 4) ? m2[2 * i]     : m1[2 * i - 8];
            const float vO = (i < 4) ? m2[2 * i + 1] : m1[2 * i - 7];
            const float nE = __int_as_float(dpp_nb(vE));
            const float nO = __int_as_float(dpp_nb(vO));
            const int pkE = pack_h2i(vE, nE);
            const int pkO = pack_h2i(nO, vO);
            lds_s[base_s + 72 * i] = odd ? pkO : pkE;
        }
        asm volatile("" ::: "memory");
        __builtin_amdgcn_sched_barrier(FENCE_MASK);

        // A-frags + MFMA (verbatim layouts)
        const int2* s2p = reinterpret_cast<const int2*>(lds_s);
        const v4h a0 = i2_as_h4(s2p[abase + 0]);
        const v4h a1 = i2_as_h4(s2p[abase + 4]);
        const v4h a2 = i2_as_h4(s2p[abase + 8]);
        const v4h a3 = i2_as_h4(s2p[abase + 12]);
        v4f c0 = {0.f, 0.f, 0.f, 0.f}, c1 = c0, c2 = c0, c3 = c0;
        MFMA_BLOCK(c0, c1, c2, c3, a0, a1, a2, a3, wb);

        // u-redistribution: write [t'][comp] float4 (contiguous per instr)
        lds_u4[uw + 0]  = make_float4(c0[0], c0[1], c0[2], c0[3]);
        lds_u4[uw + 16] = make_float4(c1[0], c1[1], c1[2], c1[3]);
        lds_u4[uw + 32] = make_float4(c2[0], c2[1], c2[2], c2[3]);
        lds_u4[uw + 48] = make_float4(c3[0], c3[1], c3[2], c3[3]);
        asm volatile("" ::: "memory");
        __builtin_amdgcn_sched_barrier(FENCE_MASK);

        const float4 q0 = lds_u4[0 * 256 + l];  // chains 0..3  at comp l
        const float4 q1 = lds_u4[1 * 256 + l];  // chains 4..7
        const float4 q2 = lds_u4[2 * 256 + l];  // chains 8..11
        const float4 q3 = lds_u4[3 * 256 + l];  // chains 12..15

        // r = 1/(exp2(u)+1) for all 16 chains
        float rr[16];
        rr[0]  = recip_fast(exp2_fast(q0.x) + 1.f);
        rr[1]  = recip_fast(exp2_fast(q0.y) + 1.f);
        rr[2]  = recip_fast(exp2_fast(q0.z) + 1.f);
        rr[3]  = recip_fast(exp2_fast(q0.w) + 1.f);
        rr[4]  = recip_fast(exp2_fast(q1.x) + 1.f);
        rr[5]  = recip_fast(exp2_fast(q1.y) + 1.f);
        rr[6]  = recip_fast(exp2_fast(q1.z) + 1.f);
        rr[7]  = recip_fast(exp2_fast(q1.w) + 1.f);
        rr[8]  = recip_fast(exp2_fast(q2.x) + 1.f);
        rr[9]  = recip_fast(exp2_fast(q2.y) + 1.f);
        rr[10] = recip_fast(exp2_fast(q2.z) + 1.f);
        rr[11] = recip_fast(exp2_fast(q2.w) + 1.f);
        rr[12] = recip_fast(exp2_fast(q3.x) + 1.f);
        rr[13] = recip_fast(exp2_fast(q3.y) + 1.f);
        rr[14] = recip_fast(exp2_fast(q3.z) + 1.f);
        rr[15] = recip_fast(exp2_fast(q3.w) + 1.f);

        // FINALIZE block r-1 with iter-2 tanh (exact recurrence) + stores
        if (r >= 2) {
            const int k0 = 8 * (r - 2) + 1;
            #pragma unroll
            for (int j = 0; j < 8; ++j) {
                yfin = fmaf(2.f * DT_C, rr[j], fmaf(DT_C, fa[j], yfin) - DT_C);
                if (k0 + j < n) (op + j * BS)[l] = yfin;
            }
            op += 8 * BS;
        }

        // y^1(block r) with iter-1 tanh; emit iter-2 midpoints m2'
        float yb = yfin;
        #pragma unroll
        for (int j = 0; j < 8; ++j) {
            const float ybn = fmaf(2.f * DT_C, rr[8 + j],
                                   fmaf(DT_C, fb[j], yb) - DT_C);
            m2[j] = 0.5f * (yb + ybn);
            yb = ybn;
        }
        tcar = fmaf(-2.f, rr[15], 1.f);  // t1(block r, step 8)

        // predictor midpoints m1'(block r+1)
        float yh = yb;
        #pragma unroll
        for (int j = 0; j < 8; ++j) {
            const float d = fc[j] - tcar;
            m1[j] = fmaf(0.5f * DT_C, d, yh);
            yh = fmaf(DT_C, d, yh);
        }

        // rotate force blocks
        #pragma unroll
        for (int j = 0; j < 8; ++j) { fa[j] = fb[j]; fb[j] = fc[j]; fc[j] = fd[j]; }
    }
}

extern "C" void kernel_launch(void* const* d_in, const int* in_sizes, int n_in,
                              void* d_out, int out_size, void* d_ws, size_t ws_size,
                              hipStream_t stream) {
    const float* y0     = (const float*)d_in[0];   // (B, S)
    const float* forces = (const float*)d_in[1];   // (n, B, S)
    const float* W      = (const float*)d_in[2];   // (S, S)
    float* out = (float*)d_out;                    // (n, B, S)

    const int BS = in_sizes[0];       // B * S
    const int B  = BS / SDIM;         // 128
    const int n  = in_sizes[1] / BS;  // 65

    rnes_pipe_kernel<<<B, SDIM, 0, stream>>>(y0, forces, W, out, n, B);
}

// Round 23
// 15.359 us; speedup vs baseline: 1.0927x; 1.0115x over previous
//
#include <hip/hip_runtime.h>

// Sequential implicit-midpoint solve: y_k = y_{k-1} + DT*f_k - DT*tanh(W s_k),
// s_k = (y_k + y_{k-1})/2, one wave per batch element.
//
// R23 = R22 (15.53us, absmax 0.04443359) + instruction diet (numerics
// untouched, absmax must stay bit-identical):
//   1. #pragma unroll 3 on the main loop: the 24-mov force-ring rotation
//      becomes register renaming (R=9 = 3x3).
//   2. uniform guard skips the dead y1/m2/tcar/m1 tail on the last round.
//   3. uniform guard skips prefetch for rounds whose block doesn't exist.
// Cost model (R22 calibrated): round = 8 cyc/instr * N_instr + ~900 cyc
// exposed latency; diet removes ~30 instrs/round.
//
// Structure (R22): pipelined 2-iteration scheme, 16 chains/round, 8-step
// blocks. Round r: chains 0..7 = iter-2 midpoints of block r-1; 8..15 =
// iter-1 midpoints of block r. Finalize block r-1 with iter-2 tanh (exact
// recurrence); build y^1(block r) -> m2'(block r); tcar -> m1'(block r+1).
// 64 steps = 8 blocks -> 10 MFMA rounds.
// Verified machinery: wb B-frags, A-frag addressing (18c+g), MFMA_BLOCK,
// D-layout, fences (mem clobber + sched_barrier 0x7F), saddr + scalar clamps.
// W pre-scaled by 2*log2(e): tanh(Ws) = 1 - 2/(exp2(u)+1).

#define SDIM 64
#define DT_C 0.05f
#define WSCALE 2.8853900817779268f  // 2*log2(e)
#define FENCE_MASK 0x7F             // DS may not cross; all else may

typedef _Float16 v4h __attribute__((ext_vector_type(4)));
typedef float    v4f __attribute__((ext_vector_type(4)));
typedef __fp16   g2  __attribute__((ext_vector_type(2)));

#if defined(__HIP_DEVICE_COMPILE__)
#define MFMA16(A, B, C) __builtin_amdgcn_mfma_f32_16x16x16f16((A), (B), (C), 0, 0, 0)
#else
#define MFMA16(A, B, C) (C)  // host pass parses only
#endif

union H2U  { int i; g2 g; };
union V4HU { int2 i2; v4h h; g2 g[2]; };

__device__ __forceinline__ float recip_fast(float x) {
    float r; asm("v_rcp_f32 %0, %1" : "=v"(r) : "v"(x)); return r;
}
__device__ __forceinline__ float exp2_fast(float x) {
    float r; asm("v_exp_f32 %0, %1" : "=v"(r) : "v"(x)); return r;
}
__device__ __forceinline__ int pack_h2i(float a, float b) {
    H2U u; u.g = __builtin_amdgcn_cvt_pkrtz(a, b); return u.i;
}
__device__ __forceinline__ v4h pack_h4(float a, float b, float c, float d) {
    V4HU u;
    u.g[0] = __builtin_amdgcn_cvt_pkrtz(a, b);
    u.g[1] = __builtin_amdgcn_cvt_pkrtz(c, d);
    return u.h;
}
__device__ __forceinline__ v4h i2_as_h4(int2 v) { V4HU u; u.i2 = v; return u.h; }
__device__ __forceinline__ int dpp_nb(float s) {
    // quad_perm [1,0,3,2]: lane l <-> l^1
    return __builtin_amdgcn_update_dpp(0, __float_as_int(s), 0xB1, 0xF, 0xF, true);
}
__device__ __forceinline__ int imin(int a, int b) { return a < b ? a : b; }

#define MFMA_BLOCK(ac0, ac1, ac2, ac3, A0, A1, A2, A3, wb)                  \
    ac0 = MFMA16(A0, wb[0],  ac0);  ac1 = MFMA16(A0, wb[4],  ac1);          \
    ac2 = MFMA16(A0, wb[8],  ac2);  ac3 = MFMA16(A0, wb[12], ac3);          \
    ac0 = MFMA16(A1, wb[1],  ac0);  ac1 = MFMA16(A1, wb[5],  ac1);          \
    ac2 = MFMA16(A1, wb[9],  ac2);  ac3 = MFMA16(A1, wb[13], ac3);          \
    ac0 = MFMA16(A2, wb[2],  ac0);  ac1 = MFMA16(A2, wb[6],  ac1);          \
    ac2 = MFMA16(A2, wb[10], ac2);  ac3 = MFMA16(A2, wb[14], ac3);          \
    ac0 = MFMA16(A3, wb[3],  ac0);  ac1 = MFMA16(A3, wb[7],  ac1);          \
    ac2 = MFMA16(A3, wb[11], ac2);  ac3 = MFMA16(A3, wb[15], ac3)

__global__ __launch_bounds__(64) void rnes_pipe_kernel(
    const float* __restrict__ y0,
    const float* __restrict__ forces,
    const float* __restrict__ W,
    float* __restrict__ out,
    int n, int B)
{
    const int b = blockIdx.x;
    const int l = threadIdx.x;
    const bool odd = (l & 1);

    // B-operand frags (R15-verified): wb[t*4+h] = W[16t+(l&15)][16h+4*(l>>4)+kk]
    v4h wb[16];
    {
        const int co = l & 15, g = l >> 4;
        #pragma unroll
        for (int t = 0; t < 4; ++t) {
            #pragma unroll
            for (int h = 0; h < 4; ++h) {
                const float4 v = *reinterpret_cast<const float4*>(
                    W + (16 * t + co) * 64 + 16 * h + 4 * g);
                wb[t * 4 + h] = pack_h4(WSCALE * v.x, WSCALE * v.y,
                                        WSCALE * v.z, WSCALE * v.w);
            }
        }
    }

    __shared__ __align__(16) int    lds_s[576];    // 16 chains x 36 ints
    __shared__ __align__(16) float4 lds_u4[1024];  // [t'][comp] 16KB

    const int BS = B * SDIM;
    const float* frow = forces + b * SDIM;
    float*       orow = out    + b * SDIM;

    const float y0v = (y0 + b * SDIM)[l];
    orow[l] = y0v;
    float yfin = y0v;

    const int base_s = 36 * (l & 1) + (l >> 1);
    const int abase  = 18 * (l & 15) + (l >> 4);   // int2 units
    const int uw     = (l >> 4) * 256 + (l & 15);  // float4 units

    // ---- SEED round: all 16 chains = y0; tcar = tanh(W y0) ----
    float tcar;
    {
        const float nb = __int_as_float(dpp_nb(y0v));
        const int sel = odd ? pack_h2i(nb, y0v) : pack_h2i(y0v, nb);
        #pragma unroll
        for (int i = 0; i < 8; ++i) lds_s[base_s + 72 * i] = sel;
        asm volatile("" ::: "memory");
        __builtin_amdgcn_sched_barrier(FENCE_MASK);

        const int2* s2p = reinterpret_cast<const int2*>(lds_s);
        const v4h a0 = i2_as_h4(s2p[abase + 0]);
        const v4h a1 = i2_as_h4(s2p[abase + 4]);
        const v4h a2 = i2_as_h4(s2p[abase + 8]);
        const v4h a3 = i2_as_h4(s2p[abase + 12]);
        v4f c0 = {0.f, 0.f, 0.f, 0.f}, c1 = c0, c2 = c0, c3 = c0;
        MFMA_BLOCK(c0, c1, c2, c3, a0, a1, a2, a3, wb);

        lds_u4[uw + 0]  = make_float4(c0[0], c0[1], c0[2], c0[3]);
        lds_u4[uw + 16] = make_float4(c1[0], c1[1], c1[2], c1[3]);
        lds_u4[uw + 32] = make_float4(c2[0], c2[1], c2[2], c2[3]);
        lds_u4[uw + 48] = make_float4(c3[0], c3[1], c3[2], c3[3]);
        asm volatile("" ::: "memory");
        __builtin_amdgcn_sched_barrier(FENCE_MASK);

        const float4 q0 = lds_u4[l];  // chains 0..3 at comp l; chain0 = .x
        tcar = fmaf(-2.f, recip_fast(exp2_fast(q0.x) + 1.f), 1.f);
    }

    // force blocks: fa = block r-1, fb = block r, fc = block r+1
    float fa[8], fb[8], fc[8];
    #pragma unroll
    for (int j = 0; j < 8; ++j) {
        fb[j] = (frow + (size_t)imin(1 + j, n - 1) * BS)[l];
        fc[j] = (frow + (size_t)imin(9 + j, n - 1) * BS)[l];
        fa[j] = fb[j];  // dummy for r=1 (finalize skipped)
    }

    // m1 = iter-1 midpoints of block 1 (tcar predictor); m2 dummy for r=1
    float m1[8], m2[8];
    {
        float yh = y0v;
        #pragma unroll
        for (int j = 0; j < 8; ++j) {
            const float d = fb[j] - tcar;
            m1[j] = fmaf(0.5f * DT_C, d, yh);
            yh = fmaf(DT_C, d, yh);
            m2[j] = m1[j];
        }
    }

    float* op = orow + BS;                 // row 1
    const int R = ((n - 1) + 7) / 8 + 1;   // n=65 -> 9

    #pragma unroll 3
    for (int r = 1; r <= R; ++r) {
        // prefetch block r+2 forces (only if that block exists; uniform guard)
        float fd[8];
        if (r + 2 <= R) {
            #pragma unroll
            for (int j = 0; j < 8; ++j)
                fd[j] = (frow + (size_t)imin(8 * r + 9 + j, n - 1) * BS)[l];
        } else {
            #pragma unroll
            for (int j = 0; j < 8; ++j) fd[j] = 0.f;
        }

        // pack & write 16 chains: c = 0..7 -> m2[c]; c = 8..15 -> m1[c-8].
        #pragma unroll
        for (int i = 0; i < 8; ++i) {
            const float vE = (i < 4) ? m2[2 * i]     : m1[2 * i - 8];
            const float vO = (i < 4) ? m2[2 * i + 1] : m1[2 * i - 7];
            const float nE = __int_as_float(dpp_nb(vE));
            const float nO = __int_as_float(dpp_nb(vO));
            const int pkE = pack_h2i(vE, nE);
            const int pkO = pack_h2i(nO, vO);
            lds_s[base_s + 72 * i] = odd ? pkO : pkE;
        }
        asm volatile("" ::: "memory");
        __builtin_amdgcn_sched_barrier(FENCE_MASK);

        // A-frags + MFMA (verbatim layouts)
        const int2* s2p = reinterpret_cast<const int2*>(lds_s);
        const v4h a0 = i2_as_h4(s2p[abase + 0]);
        const v4h a1 = i2_as_h4(s2p[abase + 4]);
        const v4h a2 = i2_as_h4(s2p[abase + 8]);
        const v4h a3 = i2_as_h4(s2p[abase + 12]);
        v4f c0 = {0.f, 0.f, 0.f, 0.f}, c1 = c0, c2 = c0, c3 = c0;
        MFMA_BLOCK(c0, c1, c2, c3, a0, a1, a2, a3, wb);

        // u-redistribution: write [t'][comp] float4 (contiguous per instr)
        lds_u4[uw + 0]  = make_float4(c0[0], c0[1], c0[2], c0[3]);
        lds_u4[uw + 16] = make_float4(c1[0], c1[1], c1[2], c1[3]);
        lds_u4[uw + 32] = make_float4(c2[0], c2[1], c2[2], c2[3]);
        lds_u4[uw + 48] = make_float4(c3[0], c3[1], c3[2], c3[3]);
        asm volatile("" ::: "memory");
        __builtin_amdgcn_sched_barrier(FENCE_MASK);

        const float4 q0 = lds_u4[0 * 256 + l];  // chains 0..3  at comp l
        const float4 q1 = lds_u4[1 * 256 + l];  // chains 4..7
        const float4 q2 = lds_u4[2 * 256 + l];  // chains 8..11
        const float4 q3 = lds_u4[3 * 256 + l];  // chains 12..15

        // rr = 1/(exp2(u)+1); chains 0..7 feed finalize, 8..15 feed y1
        float rr[16];
        rr[0]  = recip_fast(exp2_fast(q0.x) + 1.f);
        rr[1]  = recip_fast(exp2_fast(q0.y) + 1.f);
        rr[2]  = recip_fast(exp2_fast(q0.z) + 1.f);
        rr[3]  = recip_fast(exp2_fast(q0.w) + 1.f);
        rr[4]  = recip_fast(exp2_fast(q1.x) + 1.f);
        rr[5]  = recip_fast(exp2_fast(q1.y) + 1.f);
        rr[6]  = recip_fast(exp2_fast(q1.z) + 1.f);
        rr[7]  = recip_fast(exp2_fast(q1.w) + 1.f);
        rr[8]  = recip_fast(exp2_fast(q2.x) + 1.f);
        rr[9]  = recip_fast(exp2_fast(q2.y) + 1.f);
        rr[10] = recip_fast(exp2_fast(q2.z) + 1.f);
        rr[11] = recip_fast(exp2_fast(q2.w) + 1.f);
        rr[12] = recip_fast(exp2_fast(q3.x) + 1.f);
        rr[13] = recip_fast(exp2_fast(q3.y) + 1.f);
        rr[14] = recip_fast(exp2_fast(q3.z) + 1.f);
        rr[15] = recip_fast(exp2_fast(q3.w) + 1.f);

        // FINALIZE block r-1 with iter-2 tanh (exact recurrence) + stores
        if (r >= 2) {
            const int k0 = 8 * (r - 2) + 1;
            #pragma unroll
            for (int j = 0; j < 8; ++j) {
                yfin = fmaf(2.f * DT_C, rr[j], fmaf(DT_C, fa[j], yfin) - DT_C);
                if (k0 + j < n) (op + j * BS)[l] = yfin;
            }
            op += 8 * BS;
        }

        // tail work only if block r exists as a future block (dead on r==R)
        if (r < R) {
            // y^1(block r) with iter-1 tanh; emit iter-2 midpoints m2'
            float yb = yfin;
            #pragma unroll
            for (int j = 0; j < 8; ++j) {
                const float ybn = fmaf(2.f * DT_C, rr[8 + j],
                                       fmaf(DT_C, fb[j], yb) - DT_C);
                m2[j] = 0.5f * (yb + ybn);
                yb = ybn;
            }
            tcar = fmaf(-2.f, rr[15], 1.f);  // t1(block r, step 8)

            // predictor midpoints m1'(block r+1)
            float yh = yb;
            #pragma unroll
            for (int j = 0; j < 8; ++j) {
                const float d = fc[j] - tcar;
                m1[j] = fmaf(0.5f * DT_C, d, yh);
                yh = fmaf(DT_C, d, yh);
            }
        }

        // rotate force blocks (unroll-3 renames these away)
        #pragma unroll
        for (int j = 0; j < 8; ++j) { fa[j] = fb[j]; fb[j] = fc[j]; fc[j] = fd[j]; }
    }
}

extern "C" void kernel_launch(void* const* d_in, const int* in_sizes, int n_in,
                              void* d_out, int out_size, void* d_ws, size_t ws_size,
                              hipStream_t stream) {
    const float* y0     = (const float*)d_in[0];   // (B, S)
    const float* forces = (const float*)d_in[1];   // (n, B, S)
    const float* W      = (const float*)d_in[2];   // (S, S)
    float* out = (float*)d_out;                    // (n, B, S)

    const int BS = in_sizes[0];       // B * S
    const int B  = BS / SDIM;         // 128
    const int n  = in_sizes[1] / BS;  // 65

    rnes_pipe_kernel<<<B, SDIM, 0, stream>>>(y0, forces, W, out, n, B);
}